// Round 6
// baseline (32.953 us; speedup 1.0000x reference)
//
#include <hip/hip_runtime.h>

#define DIM_HID 65536
#define NKERS   500
#define NQ      4                    // quarters per row
#define QCHUNK  (DIM_HID / NQ)       // 16384 floats per quarter

#define ITILE   16                   // i's per expand_part block
#define NIB     32                   // 32 * 16 = 512 >= 500
#define JPAD    512                  // padded j extent for partials

typedef float f4 __attribute__((ext_vector_type(4)));

// Kernel 1: partial GEMV. Block (row, q) computes
//   ws[row*4+q] = dot(W[row, q*QCHUNK:(q+1)*QCHUNK], x[q*QCHUNK:...])
// 2000 blocks x 256 threads, <=64 VGPR -> 32 waves/CU.
// NOTE: plain (cacheable) loads for W — with graph replay, W (131 MB) fits the
// 256 MB Infinity Cache, so replays can stream W from L3 above HBM rate.
__global__ __launch_bounds__(256) void gemv_part_kernel(
    const float* __restrict__ W,
    const float* __restrict__ x,
    float* __restrict__ ws)
{
    const int bid = blockIdx.x;          // 0..1999
    const int row = bid >> 2;
    const int q   = bid & 3;
    const int t   = threadIdx.x;

    const f4* __restrict__ Wq =
        reinterpret_cast<const f4*>(W + (size_t)row * DIM_HID + q * QCHUNK);
    const f4* __restrict__ xq =
        reinterpret_cast<const f4*>(x + q * QCHUNK);

    float s = 0.0f;
#pragma unroll 4
    for (int k = 0; k < 16; ++k) {
        const int idx = t + k * 256;     // coalesced
        f4 w = Wq[idx];
        f4 v = xq[idx];
        s = fmaf(w.x, v.x, s);
        s = fmaf(w.y, v.y, s);
        s = fmaf(w.z, v.z, s);
        s = fmaf(w.w, v.w, s);
    }

#pragma unroll
    for (int off = 32; off > 0; off >>= 1)
        s += __shfl_down(s, off, 64);

    __shared__ float wsum[4];
    const int wave = t >> 6;
    const int lane = t & 63;
    if (lane == 0) wsum[wave] = s;
    __syncthreads();

    if (t == 0)
        ws[bid] = (wsum[0] + wsum[1]) + (wsum[2] + wsum[3]);
}

// Kernel 2: coalesced expand partials. Block ib covers i in [ib*16, ib*16+16);
// thread t owns columns j0=t and j1=t+256. kernels[i*500+j] reads are
// coalesced across lanes; all 16 i-iterations are independent (unrolled, one
// latency wait). partial[ib*512 + j] = sum over the block's i-range.
__global__ __launch_bounds__(256) void expand_part_kernel(
    const float* __restrict__ ws,
    const float* __restrict__ bias,
    const float* __restrict__ kernels,
    const int* __restrict__ kw,
    float* __restrict__ partial)
{
    const int ib = blockIdx.x;
    const int t  = threadIdx.x;
    const int j0 = t;
    const int j1 = t + 256;
    const f4* __restrict__ wsv = reinterpret_cast<const f4*>(ws);

    float a0 = 0.0f, a1 = 0.0f;
#pragma unroll
    for (int ii = 0; ii < ITILE; ++ii) {
        const int i = ib * ITILE + ii;
        if (i < NKERS) {
            const f4  p  = wsv[i];                         // 4 gemv partials of row i
            const float yi = ((p.x + p.y) + (p.z + p.w)) + bias[i];
            const int   w  = kw[i];
            const float* krow = kernels + i * NKERS;
            const float k0 = krow[j0];
            const float k1 = (j1 < NKERS) ? krow[j1] : 0.0f;
            if (j0 < w) a0 = fmaf(yi, k0, a0);
            if (j1 < w) a1 = fmaf(yi, k1, a1);
        }
    }
    partial[ib * JPAD + j0] = a0;
    partial[ib * JPAD + j1] = a1;
}

// Kernel 3: z[j] = sum_ib partial[ib*512 + j]. 32 independent coalesced loads.
__global__ __launch_bounds__(512) void expand_reduce_kernel(
    const float* __restrict__ partial,
    float* __restrict__ z)
{
    const int j = threadIdx.x;
    if (j >= NKERS) return;
    float s = 0.0f;
#pragma unroll
    for (int ib = 0; ib < NIB; ++ib)
        s += partial[ib * JPAD + j];
    z[j] = s;
}

extern "C" void kernel_launch(void* const* d_in, const int* in_sizes, int n_in,
                              void* d_out, int out_size, void* d_ws, size_t ws_size,
                              hipStream_t stream)
{
    const float* input   = (const float*)d_in[0];  // [65536]
    const float* weight  = (const float*)d_in[1];  // [500, 65536]
    const float* bias    = (const float*)d_in[2];  // [500]
    const float* kernels = (const float*)d_in[3];  // [500, 500]
    const int*   kwidths = (const int*)d_in[4];    // [500]
    float* z  = (float*)d_out;                     // [500]
    float* ws = (float*)d_ws;                      // [0..2000): gemv partials
    float* pz = ws + 4096;                         // [4096..4096+32*512): expand partials

    gemv_part_kernel<<<NKERS * NQ, 256, 0, stream>>>(weight, input, ws);
    expand_part_kernel<<<NIB, 256, 0, stream>>>(ws, bias, kernels, kwidths, pz);
    expand_reduce_kernel<<<1, 512, 0, stream>>>(pz, z);
}